// Round 4
// baseline (581.619 us; speedup 1.0000x reference)
//
#include <hip/hip_runtime.h>

// EMD via Sinkhorn on 64 Hamming states, eps=0.1.
// K = exp(-C/eps) = tensor product of six 2x2 [[1,a],[a,1]], a = exp(-10)
//   => K-apply is 6 butterfly stages (384 FMA), not a 64x64 matvec.
// Scale invariance: the Sinkhorn map is 1-homogeneous => iterate on RAW p,q;
// the single surviving factor 1/sum(p) is applied in the epilogue.
// EMD readout (w = K v_final, u = p/w):
//   emd = (a * sum_b u.X_b w) / ((1-a^2) * sum(p)) - 6a^2/(1-a^2)
//
// R3 post-mortem: pins stopped global remat, but 192 live floats forced p,q
// into AGPRs (VGPR=108 + ~128 AGPR => 2 waves/SIMD); each half-step paid 64
// v_accvgpr_read of VALU time (~8%). Fix here: q lives in LDS, TRANSPOSED
// (qs[state][tid]) so the divide-step read is 64 consecutive addresses --
// conflict-free, on the LDS pipe, overlapped with the butterfly's VALU work.
// Register state is now w[64]+p[64]+temps ~ 150 => p stays in true VGPRs.

namespace {

constexpr int   N     = 64;
constexpr int   NBITS = 6;
constexpr int   ITERS = 50;
constexpr int   BLOCK = 128;

constexpr double Ad = 4.5399929762484854e-05;           // exp(-10)
constexpr float  A  = (float)Ad;
constexpr float  EMD_SCALE = (float)(Ad / (1.0 - Ad * Ad));
constexpr float  EMD_DIAG  = (float)(6.0 * Ad * Ad / (1.0 - Ad * Ad));

__device__ __forceinline__ float rcp(float x) { return __builtin_amdgcn_rcpf(x); }

// In-place w <- K w (K symmetric; serves both u@K and v@K^T).
__device__ __forceinline__ void butterfly(float w[N]) {
#pragma unroll
  for (int b = 0; b < NBITS; ++b) {
#pragma unroll
    for (int i = 0; i < N; ++i) {
      if ((i & (1 << b)) == 0) {
        const int j = i | (1 << b);
        const float wi = w[i];
        const float wj = w[j];
        w[i] = fmaf(A, wj, wi);
        w[j] = fmaf(A, wi, wj);
      }
    }
  }
}

__global__ __launch_bounds__(BLOCK, 2) void emd_sinkhorn_kernel(
    const float* __restrict__ gp, const float* __restrict__ gq,
    float* __restrict__ out, int nbatch) {
  const int tid = threadIdx.x;
  const int b = blockIdx.x * BLOCK + tid;

  // q transposed in LDS: qs[state][tid]. Divide-step read: lane t reads
  // qs[i][t] -> 64 consecutive dwords -> 2 lanes/bank -> conflict-free.
  __shared__ float qs[N][BLOCK];  // 32 KiB

  if (b < nbatch) {
    const float4* __restrict__ q4 =
        reinterpret_cast<const float4*>(gq) + (size_t)b * (N / 4);
#pragma unroll
    for (int k = 0; k < N / 4; ++k) {
      const float4 t = q4[k];
      qs[4 * k + 0][tid] = t.x;
      qs[4 * k + 1][tid] = t.y;
      qs[4 * k + 2][tid] = t.z;
      qs[4 * k + 3][tid] = t.w;
    }
  }
  __syncthreads();
  if (b >= nbatch) return;

  const float4* __restrict__ p4 =
      reinterpret_cast<const float4*>(gp) + (size_t)b * (N / 4);

  float p[N], w[N];

  // Load p ONCE; pin each element so the load cannot be rematerialized.
#pragma unroll
  for (int k = 0; k < N / 4; ++k) {
    const float4 t = p4[k];
    p[4 * k + 0] = t.x;
    p[4 * k + 1] = t.y;
    p[4 * k + 2] = t.z;
    p[4 * k + 3] = t.w;
  }
#pragma unroll
  for (int i = 0; i < N; ++i) asm volatile("" : "+v"(p[i]));

  // u0 = ones => K u0 propto ones => v1 propto q (scale drops out).
#pragma unroll
  for (int i = 0; i < N; ++i) w[i] = qs[i][tid];

  // 49 full iterations: u_k = p/(K v_k); v_{k+1} = q/(K u_k)  (up to scalars).
#pragma unroll 1
  for (int it = 0; it < ITERS - 1; ++it) {
    butterfly(w);  // K v_k
#pragma unroll
    for (int i = 0; i < N; ++i) w[i] = p[i] * rcp(w[i]);  // u_k
    butterfly(w);  // K u_k
#pragma unroll
    for (int i = 0; i < N; ++i) w[i] = qs[i][tid] * rcp(w[i]);  // v_{k+1}
  }

  // w = K v_50 ; u_50 = p/w formed on the fly in the readout.
  butterfly(w);

  float sp = 0.f;  // sum(p) -- the only surviving normalization factor
  float sx = 0.f;  // sum_i u_i * sum_b w[i^b]
#pragma unroll
  for (int i = 0; i < N; ++i) {
    sp += p[i];
    const float ui = p[i] * rcp(w[i]);
    float nb = w[i ^ 1];
#pragma unroll
    for (int bb = 1; bb < NBITS; ++bb) nb += w[i ^ (1 << bb)];
    sx = fmaf(ui, nb, sx);
  }

  out[b] = fmaf(sx * rcp(sp), EMD_SCALE, -EMD_DIAG);
}

}  // namespace

extern "C" void kernel_launch(void* const* d_in, const int* in_sizes, int n_in,
                              void* d_out, int out_size, void* d_ws, size_t ws_size,
                              hipStream_t stream) {
  const float* p = (const float*)d_in[0];
  const float* q = (const float*)d_in[1];
  // d_in[2] is the Hamming cost matrix; its tensor-product structure is
  // hardcoded (a = exp(-1/eps) = exp(-10)).
  float* out = (float*)d_out;

  const int nbatch = in_sizes[0] / N;  // 262144
  const int grid = (nbatch + BLOCK - 1) / BLOCK;
  emd_sinkhorn_kernel<<<grid, BLOCK, 0, stream>>>(p, q, out, nbatch);
}

// Round 5
// 390.974 us; speedup vs baseline: 1.4876x; 1.4876x over previous
//
#include <hip/hip_runtime.h>

// EMD via Sinkhorn on 64 Hamming states, eps=0.1.
// K = exp(-C/eps) = tensor product of six 2x2 [[1,a],[a,1]], a = exp(-10)
//   => K-apply is 6 butterfly stages, here executed as PACKED fp32
//      (v_pk_fma_f32, 2 FMA/lane/inst, full rate on CDNA): 192 pk_fma.
// Scale invariance (map is 1-homogeneous): iterate on raw p and q scaled by
// sum(p)/sum(q) (kills the (sum_p/sum_q)^50 drift; output-invariant). The
// single surviving factor 1/sum(p) is applied in the epilogue.
// Divide steps use the batched-inverse pair trick: one rcp serves TWO
// states: r=rcp(w_i*w_j); 1/w_i = w_j*r; 1/w_j = w_i*r  (rcp is 1/4-rate,
// mul is full-rate => halves the transcendental bill).
// EMD readout (w = K v_final, u = p/w):
//   emd = (a * sum_b u.X_b w) / ((1-a^2) * sum(p)) - 6a^2/(1-a^2)
//
// R4 post-mortem: LDS-q regressed (scattered ds_read latency unhidden at 2
// waves/SIMD; occupancy fell). Reverted to R3 register structure (93%
// VALUBusy); this round cuts the VALU work itself (packed FMA + paired rcp).

namespace {

typedef float v2f __attribute__((ext_vector_type(2)));

constexpr int   N     = 64;
constexpr int   NP    = 32;   // register pairs; pair k = states {2k, 2k+1}
constexpr int   NBITS = 6;
constexpr int   ITERS = 50;

constexpr double Ad = 4.5399929762484854e-05;           // exp(-10)
constexpr float  A  = (float)Ad;
constexpr float  EMD_SCALE = (float)(Ad / (1.0 - Ad * Ad));
constexpr float  EMD_DIAG  = (float)(6.0 * Ad * Ad / (1.0 - Ad * Ad));

__device__ __forceinline__ float rcp(float x) { return __builtin_amdgcn_rcpf(x); }

// Packed butterfly: W <- K W across 32 register pairs.
__device__ __forceinline__ void butterfly_pk(v2f W[NP], v2f A2) {
  // bit 0: partner is the other half of the same pair -> op_sel-swapped src1.
  // D.lo = a*W.hi + W.lo ; D.hi = a*W.lo + W.hi
#pragma unroll
  for (int k = 0; k < NP; ++k) {
    v2f d;
    asm("v_pk_fma_f32 %0, %1, %2, %3 op_sel:[0,1,0] op_sel_hi:[1,0,1]"
        : "=v"(d) : "v"(A2), "v"(W[k]), "v"(W[k]));
    W[k] = d;
  }
  // bits 1..5: partner pair j = k ^ (1<<(b-1)); halves stay aligned.
#pragma unroll
  for (int b = 1; b < NBITS; ++b) {
    const int m = 1 << (b - 1);
#pragma unroll
    for (int k = 0; k < NP; ++k) {
      if ((k & m) == 0) {
        const int j = k | m;
        const v2f t0 = W[k], t1 = W[j];
        v2f d0, d1;
        asm("v_pk_fma_f32 %0, %1, %2, %3" : "=v"(d0) : "v"(A2), "v"(t1), "v"(t0));
        asm("v_pk_fma_f32 %0, %1, %2, %3" : "=v"(d1) : "v"(A2), "v"(t0), "v"(t1));
        W[k] = d0;
        W[j] = d1;
      }
    }
  }
}

// W <- X / W elementwise, one rcp per PAIR (batched-inverse trick).
__device__ __forceinline__ void div_step(v2f W[NP], const v2f X[NP]) {
#pragma unroll
  for (int k = 0; k < NP; ++k) {
    const float wl = W[k].x, wh = W[k].y;
    const float r = rcp(wl * wh);
    W[k].x = (X[k].x * wh) * r;   // = X.lo / wl
    W[k].y = (X[k].y * wl) * r;   // = X.hi / wh
  }
}

__global__ __launch_bounds__(256, 2) void emd_sinkhorn_kernel(
    const float* __restrict__ gp, const float* __restrict__ gq,
    float* __restrict__ out, int nbatch) {
  const int b = blockIdx.x * 256 + threadIdx.x;
  if (b >= nbatch) return;

  const float4* __restrict__ p4 =
      reinterpret_cast<const float4*>(gp) + (size_t)b * (N / 4);
  const float4* __restrict__ q4 =
      reinterpret_cast<const float4*>(gq) + (size_t)b * (N / 4);

  v2f P[NP], Q[NP], W[NP];

  // Load p,q ONCE, repack into register pairs.
#pragma unroll
  for (int k = 0; k < N / 4; ++k) {
    const float4 tp = p4[k];
    P[2 * k + 0] = v2f{tp.x, tp.y};
    P[2 * k + 1] = v2f{tp.z, tp.w};
    const float4 tq = q4[k];
    Q[2 * k + 0] = v2f{tq.x, tq.y};
    Q[2 * k + 1] = v2f{tq.z, tq.w};
  }

  // Scale q by sum(p)/sum(q): output-invariant (1-homogeneous map), kills
  // the (sum_p/sum_q)^50 magnitude drift of the unnormalized iteration.
  float sp0 = 0.f, sq0 = 0.f;
#pragma unroll
  for (int k = 0; k < NP; ++k) {
    sp0 += P[k].x + P[k].y;
    sq0 += Q[k].x + Q[k].y;
  }
  const float qscale = sp0 * rcp(sq0);
#pragma unroll
  for (int k = 0; k < NP; ++k) {
    Q[k].x *= qscale;
    Q[k].y *= qscale;
  }

  // Pin p,q in registers: values become opaque -> no global-load remat.
#pragma unroll
  for (int k = 0; k < NP; ++k) {
    asm volatile("" : "+v"(P[k]));
    asm volatile("" : "+v"(Q[k]));
  }

  v2f A2 = v2f{A, A};
  asm volatile("" : "+v"(A2));  // keep resident (VOP3P cannot take literals)

  // u0 = ones => K u0 propto ones => v1 propto q (scale drops out).
#pragma unroll
  for (int k = 0; k < NP; ++k) W[k] = Q[k];

  // 49 full iterations: u = p/(K v); v' = q/(K u)  (up to global scalars).
#pragma unroll 1
  for (int it = 0; it < ITERS - 1; ++it) {
    butterfly_pk(W, A2);
    div_step(W, P);
    butterfly_pk(W, A2);
    div_step(W, Q);
  }

  // w = K v_50 ; u_50 = p/w formed on the fly in the readout.
  butterfly_pk(W, A2);

  float ws[N];
#pragma unroll
  for (int k = 0; k < NP; ++k) {
    ws[2 * k + 0] = W[k].x;
    ws[2 * k + 1] = W[k].y;
  }

  float sp = 0.f;  // sum(p) -- the only surviving normalization factor
  float sx = 0.f;  // sum_i u_i * sum_b w[i^b]
#pragma unroll
  for (int k = 0; k < NP; ++k) {
#pragma unroll
    for (int h = 0; h < 2; ++h) {
      const int i = 2 * k + h;
      const float pi = h ? P[k].y : P[k].x;
      sp += pi;
      const float ui = pi * rcp(ws[i]);
      float nb = ws[i ^ 1];
#pragma unroll
      for (int bb = 1; bb < NBITS; ++bb) nb += ws[i ^ (1 << bb)];
      sx = fmaf(ui, nb, sx);
    }
  }

  out[b] = fmaf(sx * rcp(sp), EMD_SCALE, -EMD_DIAG);
}

}  // namespace

extern "C" void kernel_launch(void* const* d_in, const int* in_sizes, int n_in,
                              void* d_out, int out_size, void* d_ws, size_t ws_size,
                              hipStream_t stream) {
  const float* p = (const float*)d_in[0];
  const float* q = (const float*)d_in[1];
  // d_in[2] is the Hamming cost matrix; its tensor-product structure is
  // hardcoded (a = exp(-1/eps) = exp(-10)).
  float* out = (float*)d_out;

  const int nbatch = in_sizes[0] / N;  // 262144
  const int block = 256;
  const int grid = (nbatch + block - 1) / block;
  emd_sinkhorn_kernel<<<grid, block, 0, stream>>>(p, q, out, nbatch);
}

// Round 6
// 378.540 us; speedup vs baseline: 1.5365x; 1.0328x over previous
//
#include <hip/hip_runtime.h>

// EMD via Sinkhorn on 64 Hamming states, eps=0.1.
// K = exp(-C/eps) = tensor product of six 2x2 [[1,a],[a,1]], a = exp(-10)
//   => K-apply is 6 butterfly stages as PACKED fp32 (v_pk_fma_f32 is
//      full-rate on gfx950 -- R5's 0.74x delta only fits that model).
// Scale invariance (map is 1-homogeneous): iterate on raw p and q scaled by
// sum(p)/sum(q); the single surviving 1/sum(p) is applied in the epilogue.
// Divide steps: batched-inverse pair trick (one rcp per 2 states; quad
// version rejected: u,v contrast reaches ~1/a^6 ~ 1e26, 4-products would
// overflow fp32) -- now fully packed:
//   c  = v_pk_mul(X, W.swapped)        ; {X.lo*wh, X.hi*wl}
//   W' = v_pk_mul(c, r broadcast-low)  ; r = rcp(wl*wh) lives in the LOW
//        half of a v2f; op_sel_hi:[..,0] never reads the undef high half,
//        so the scalar broadcast costs zero v_movs.
// EMD readout (w = K v_final, u = p/w):
//   emd = (a * sum_b u.X_b w) / ((1-a^2) * sum(p)) - 6a^2/(1-a^2)

namespace {

typedef float v2f __attribute__((ext_vector_type(2)));

constexpr int   N     = 64;
constexpr int   NP    = 32;   // register pairs; pair k = states {2k, 2k+1}
constexpr int   NBITS = 6;
constexpr int   ITERS = 50;

constexpr double Ad = 4.5399929762484854e-05;           // exp(-10)
constexpr float  A  = (float)Ad;
constexpr float  EMD_SCALE = (float)(Ad / (1.0 - Ad * Ad));
constexpr float  EMD_DIAG  = (float)(6.0 * Ad * Ad / (1.0 - Ad * Ad));

__device__ __forceinline__ float rcp(float x) { return __builtin_amdgcn_rcpf(x); }

// Packed butterfly: W <- K W across 32 register pairs.
__device__ __forceinline__ void butterfly_pk(v2f W[NP], v2f A2) {
  // bit 0: partner is the other half of the same pair -> op_sel-swapped src1.
  // D.lo = a*W.hi + W.lo ; D.hi = a*W.lo + W.hi
#pragma unroll
  for (int k = 0; k < NP; ++k) {
    v2f d;
    asm("v_pk_fma_f32 %0, %1, %2, %3 op_sel:[0,1,0] op_sel_hi:[1,0,1]"
        : "=v"(d) : "v"(A2), "v"(W[k]), "v"(W[k]));
    W[k] = d;
  }
  // bits 1..5: partner pair j = k ^ (1<<(b-1)); halves stay aligned.
#pragma unroll
  for (int b = 1; b < NBITS; ++b) {
    const int m = 1 << (b - 1);
#pragma unroll
    for (int k = 0; k < NP; ++k) {
      if ((k & m) == 0) {
        const int j = k | m;
        const v2f t0 = W[k], t1 = W[j];
        v2f d0, d1;
        asm("v_pk_fma_f32 %0, %1, %2, %3" : "=v"(d0) : "v"(A2), "v"(t1), "v"(t0));
        asm("v_pk_fma_f32 %0, %1, %2, %3" : "=v"(d1) : "v"(A2), "v"(t0), "v"(t1));
        W[k] = d0;
        W[j] = d1;
      }
    }
  }
}

// W <- X / W elementwise, one rcp per PAIR, fully packed.
__device__ __forceinline__ void div_step(v2f W[NP], const v2f X[NP]) {
#pragma unroll
  for (int k = 0; k < NP; ++k) {
    v2f rv;
    rv.x = rcp(W[k].x * W[k].y);   // r in low half; high half never read
    v2f c, d;
    // c = {X.lo * W.hi, X.hi * W.lo}
    asm("v_pk_mul_f32 %0, %1, %2 op_sel:[0,1] op_sel_hi:[1,0]"
        : "=v"(c) : "v"(X[k]), "v"(W[k]));
    // W' = c * {r, r}  (src1 low half broadcast to both lanes)
    asm("v_pk_mul_f32 %0, %1, %2 op_sel:[0,0] op_sel_hi:[1,0]"
        : "=v"(d) : "v"(c), "v"(rv));
    W[k] = d;
  }
}

__global__ __launch_bounds__(256, 2) void emd_sinkhorn_kernel(
    const float* __restrict__ gp, const float* __restrict__ gq,
    float* __restrict__ out, int nbatch) {
  const int b = blockIdx.x * 256 + threadIdx.x;
  if (b >= nbatch) return;

  const float4* __restrict__ p4 =
      reinterpret_cast<const float4*>(gp) + (size_t)b * (N / 4);
  const float4* __restrict__ q4 =
      reinterpret_cast<const float4*>(gq) + (size_t)b * (N / 4);

  v2f P[NP], Q[NP], W[NP];

  // Load p,q ONCE, repack into register pairs.
#pragma unroll
  for (int k = 0; k < N / 4; ++k) {
    const float4 tp = p4[k];
    P[2 * k + 0] = v2f{tp.x, tp.y};
    P[2 * k + 1] = v2f{tp.z, tp.w};
    const float4 tq = q4[k];
    Q[2 * k + 0] = v2f{tq.x, tq.y};
    Q[2 * k + 1] = v2f{tq.z, tq.w};
  }

  // Scale q by sum(p)/sum(q): output-invariant (1-homogeneous map), kills
  // the (sum_p/sum_q)^50 magnitude drift of the unnormalized iteration.
  float sp0 = 0.f, sq0 = 0.f;
#pragma unroll
  for (int k = 0; k < NP; ++k) {
    sp0 += P[k].x + P[k].y;
    sq0 += Q[k].x + Q[k].y;
  }
  const float qscale = sp0 * rcp(sq0);
#pragma unroll
  for (int k = 0; k < NP; ++k) {
    Q[k].x *= qscale;
    Q[k].y *= qscale;
  }

  // Pin p,q in registers: values become opaque -> no global-load remat.
#pragma unroll
  for (int k = 0; k < NP; ++k) {
    asm volatile("" : "+v"(P[k]));
    asm volatile("" : "+v"(Q[k]));
  }

  v2f A2 = v2f{A, A};
  asm volatile("" : "+v"(A2));  // keep resident (VOP3P cannot take literals)

  // u0 = ones => K u0 propto ones => v1 propto q (scale drops out).
#pragma unroll
  for (int k = 0; k < NP; ++k) W[k] = Q[k];

  // 49 full iterations: u = p/(K v); v' = q/(K u)  (up to global scalars).
#pragma unroll 1
  for (int it = 0; it < ITERS - 1; ++it) {
    butterfly_pk(W, A2);
    div_step(W, P);
    butterfly_pk(W, A2);
    div_step(W, Q);
  }

  // w = K v_50 ; u_50 = p/w formed on the fly in the readout.
  butterfly_pk(W, A2);

  float ws[N];
#pragma unroll
  for (int k = 0; k < NP; ++k) {
    ws[2 * k + 0] = W[k].x;
    ws[2 * k + 1] = W[k].y;
  }

  float sp = 0.f;  // sum(p) -- the only surviving normalization factor
  float sx = 0.f;  // sum_i u_i * sum_b w[i^b]
#pragma unroll
  for (int k = 0; k < NP; ++k) {
#pragma unroll
    for (int h = 0; h < 2; ++h) {
      const int i = 2 * k + h;
      const float pi = h ? P[k].y : P[k].x;
      sp += pi;
      const float ui = pi * rcp(ws[i]);
      float nb = ws[i ^ 1];
#pragma unroll
      for (int bb = 1; bb < NBITS; ++bb) nb += ws[i ^ (1 << bb)];
      sx = fmaf(ui, nb, sx);
    }
  }

  out[b] = fmaf(sx * rcp(sp), EMD_SCALE, -EMD_DIAG);
}

}  // namespace

extern "C" void kernel_launch(void* const* d_in, const int* in_sizes, int n_in,
                              void* d_out, int out_size, void* d_ws, size_t ws_size,
                              hipStream_t stream) {
  const float* p = (const float*)d_in[0];
  const float* q = (const float*)d_in[1];
  // d_in[2] is the Hamming cost matrix; its tensor-product structure is
  // hardcoded (a = exp(-1/eps) = exp(-10)).
  float* out = (float*)d_out;

  const int nbatch = in_sizes[0] / N;  // 262144
  const int block = 256;
  const int grid = (nbatch + block - 1) / block;
  emd_sinkhorn_kernel<<<grid, block, 0, stream>>>(p, q, out, nbatch);
}